// Round 10
// baseline (406.350 us; speedup 1.0000x reference)
//
#include <hip/hip_runtime.h>
#include <math.h>

#define Sn 4
#define Bn 8
#define Ln 512
#define Dn 128
#define Hn 128
#define NOPn 64
#define Wn 2048

// ESTABLISHED: inputs fp32 insertion order; output fp32; bf16-space compare
// (thr 3.6e-2); ws = 512MB; harness tax ~220-260us/iter; poison fill 78us.
// R21 354 (3k). R22-R26: in-kernel completion schemes all lose to the kernel
// boundary. R27 350.6: bf16 upWbf + fused ww&wem + k-split. R28 345.0: wide
// loads. R29 FAIL 361.7: 2 slots/block (lost TLP). R30 339.2 (best): XCD
// swizzle b=bid&7 -> per-XCD L2 working set ~1.1MB. mega still ~65us,
// latency-bound: 4-wave lockstep block, 3 barriers, ~3 blocks/CU concurrency,
// block lifetime ~20us vs ~5us work.
// R31 (this): ONE WAVE = ONE SLOT, ZERO BARRIERS. Wave-private LDS kidx/sidx
// (within-wave DS ordering needs no barrier), lane-owns-2-dims gathers,
// per-wave GEMV with shfl j-reduction. Grid 1024 (8b x 128 groups, swizzle
// kept) -> ~2976 active waves ALL resident at once; duration ~ one slot's
// serial latency instead of ~4 sequential refills.

__device__ __forceinline__ float bf2f(unsigned short u) {
    return __uint_as_float(((unsigned int)u) << 16);
}
__device__ __forceinline__ float bflo(unsigned int u) {
    return __uint_as_float(u << 16);
}
__device__ __forceinline__ float bfhi(unsigned int u) {
    return __uint_as_float(u & 0xFFFF0000u);
}
__device__ __forceinline__ unsigned short f2bf(float f) {
    unsigned int u = __float_as_uint(f);
    return (unsigned short)((u + 0x7FFFu + ((u >> 16) & 1u)) >> 16);  // RNE
}

// ---------------------------------------------------------------------------
// prep_k: blockIdx branches.
//   0..255   : dual GEMM tile (wkh/wsh from word_outputs)
//   256..263 : op-embedding GEMM tile (oph)
//   264..271 : compact pooled indices for b = bid-264 (cap 512)
//   272      : zero gwacc
//   273..274 : convert upW (384x128 fp32) -> upWbf (bf16)
// ---------------------------------------------------------------------------
__global__ __launch_bounds__(256) void prep_k(const float* __restrict__ A,
                                              const float* __restrict__ W1,
                                              const float* __restrict__ W2,
                                              const float* __restrict__ b1,
                                              const float* __restrict__ b2,
                                              unsigned short* __restrict__ C1,
                                              unsigned short* __restrict__ C2,
                                              const float* __restrict__ ope,
                                              const float* __restrict__ owW,
                                              const float* __restrict__ owb,
                                              unsigned short* __restrict__ oph,
                                              const float* __restrict__ goal,
                                              const float* __restrict__ wes,
                                              int* __restrict__ widx,
                                              int* __restrict__ wcnt,
                                              float* __restrict__ gwacc,
                                              const float* __restrict__ upW,
                                              unsigned short* __restrict__ upWbf) {
    __shared__ __align__(16) float lA[32][68];
    __shared__ __align__(16) float lW1[32][132];
    __shared__ __align__(16) float lW2[32][132];
    __shared__ int cnt;
    const int bid = blockIdx.x, tid = threadIdx.x;

    if (bid < 256) {  // ---- dual GEMM ----
        const int m0 = bid * 64;
        float acc1[4][8] = {}, acc2[4][8] = {};
        const int r0 = (tid & 15) * 4;
        const int h0 = (tid >> 4) * 8;
        for (int k0 = 0; k0 < 128; k0 += 32) {
            __syncthreads();
            {
                const int r = tid >> 2, kk = (tid & 3) * 8;
                const float* src = A + (size_t)(m0 + r) * 128 + (k0 + kk);
                float4 v0 = reinterpret_cast<const float4*>(src)[0];
                float4 v1 = reinterpret_cast<const float4*>(src)[1];
                lA[kk + 0][r] = v0.x; lA[kk + 1][r] = v0.y;
                lA[kk + 2][r] = v0.z; lA[kk + 3][r] = v0.w;
                lA[kk + 4][r] = v1.x; lA[kk + 5][r] = v1.y;
                lA[kk + 6][r] = v1.z; lA[kk + 7][r] = v1.w;
            }
            {
                const int kk = tid >> 3, hh = (tid & 7) * 16;
                const float* s1 = W1 + (size_t)(k0 + kk) * 128 + hh;
                const float* s2 = W2 + (size_t)(k0 + kk) * 128 + hh;
#pragma unroll
                for (int q = 0; q < 4; ++q) {
                    float4 v1 = reinterpret_cast<const float4*>(s1)[q];
                    float4 v2 = reinterpret_cast<const float4*>(s2)[q];
                    lW1[kk][hh + 4 * q + 0] = v1.x; lW1[kk][hh + 4 * q + 1] = v1.y;
                    lW1[kk][hh + 4 * q + 2] = v1.z; lW1[kk][hh + 4 * q + 3] = v1.w;
                    lW2[kk][hh + 4 * q + 0] = v2.x; lW2[kk][hh + 4 * q + 1] = v2.y;
                    lW2[kk][hh + 4 * q + 2] = v2.z; lW2[kk][hh + 4 * q + 3] = v2.w;
                }
            }
            __syncthreads();
#pragma unroll
            for (int k = 0; k < 32; ++k) {
                float4 a   = *reinterpret_cast<const float4*>(&lA[k][r0]);
                float4 w10 = *reinterpret_cast<const float4*>(&lW1[k][h0]);
                float4 w11 = *reinterpret_cast<const float4*>(&lW1[k][h0 + 4]);
                float4 w20 = *reinterpret_cast<const float4*>(&lW2[k][h0]);
                float4 w21 = *reinterpret_cast<const float4*>(&lW2[k][h0 + 4]);
                float av[4] = {a.x, a.y, a.z, a.w};
                float wv1[8] = {w10.x, w10.y, w10.z, w10.w, w11.x, w11.y, w11.z, w11.w};
                float wv2[8] = {w20.x, w20.y, w20.z, w20.w, w21.x, w21.y, w21.z, w21.w};
#pragma unroll
                for (int i = 0; i < 4; ++i)
#pragma unroll
                    for (int j = 0; j < 8; ++j) {
                        acc1[i][j] = fmaf(av[i], wv1[j], acc1[i][j]);
                        acc2[i][j] = fmaf(av[i], wv2[j], acc2[i][j]);
                    }
            }
        }
#pragma unroll
        for (int i = 0; i < 4; ++i) {
            alignas(16) unsigned short u1[8], u2[8];
#pragma unroll
            for (int j = 0; j < 8; ++j) {
                u1[j] = f2bf(acc1[i][j] + b1[h0 + j]);
                u2[j] = f2bf(acc2[i][j] + b2[h0 + j]);
            }
            const size_t off = (size_t)(m0 + r0 + i) * 128 + h0;
            *reinterpret_cast<uint4*>(C1 + off) = *reinterpret_cast<const uint4*>(u1);
            *reinterpret_cast<uint4*>(C2 + off) = *reinterpret_cast<const uint4*>(u2);
        }
    } else if (bid < 264) {  // ---- oph GEMM ----
        const int m0 = (bid - 256) * 64;
        float acc[4][8] = {};
        const int r0 = (tid & 15) * 4;
        const int h0 = (tid >> 4) * 8;
        for (int k0 = 0; k0 < 128; k0 += 32) {
            __syncthreads();
            {
                const int r = tid >> 2, kk = (tid & 3) * 8;
                const float* src = ope + (size_t)(m0 + r) * 128 + (k0 + kk);
                float4 v0 = reinterpret_cast<const float4*>(src)[0];
                float4 v1 = reinterpret_cast<const float4*>(src)[1];
                lA[kk + 0][r] = v0.x; lA[kk + 1][r] = v0.y;
                lA[kk + 2][r] = v0.z; lA[kk + 3][r] = v0.w;
                lA[kk + 4][r] = v1.x; lA[kk + 5][r] = v1.y;
                lA[kk + 6][r] = v1.z; lA[kk + 7][r] = v1.w;
            }
            {
                const int kk = tid >> 3, hh = (tid & 7) * 16;
                const float* src = owW + (size_t)(k0 + kk) * 128 + hh;
#pragma unroll
                for (int q = 0; q < 4; ++q) {
                    float4 v = reinterpret_cast<const float4*>(src)[q];
                    lW1[kk][hh + 4 * q + 0] = v.x; lW1[kk][hh + 4 * q + 1] = v.y;
                    lW1[kk][hh + 4 * q + 2] = v.z; lW1[kk][hh + 4 * q + 3] = v.w;
                }
            }
            __syncthreads();
#pragma unroll
            for (int k = 0; k < 32; ++k) {
                float4 a  = *reinterpret_cast<const float4*>(&lA[k][r0]);
                float4 w0 = *reinterpret_cast<const float4*>(&lW1[k][h0]);
                float4 w1 = *reinterpret_cast<const float4*>(&lW1[k][h0 + 4]);
                float av[4] = {a.x, a.y, a.z, a.w};
                float wv[8] = {w0.x, w0.y, w0.z, w0.w, w1.x, w1.y, w1.z, w1.w};
#pragma unroll
                for (int i = 0; i < 4; ++i)
#pragma unroll
                    for (int j = 0; j < 8; ++j) acc[i][j] = fmaf(av[i], wv[j], acc[i][j]);
            }
        }
#pragma unroll
        for (int i = 0; i < 4; ++i) {
            alignas(16) unsigned short us[8];
#pragma unroll
            for (int j = 0; j < 8; ++j) us[j] = f2bf(acc[i][j] + owb[h0 + j]);
            *reinterpret_cast<uint4*>(oph + (size_t)(m0 + r0 + i) * 128 + h0) =
                *reinterpret_cast<const uint4*>(us);
        }
    } else if (bid < 272) {  // ---- compact (cap 512) ----
        const int b = bid - 264;
        if (tid == 0) cnt = 0;
        __syncthreads();
#pragma unroll
        for (int j = 0; j < 8; ++j) {
            const int w = tid * 8 + j;
            if (goal[b * Wn + w] != 0.f && wes[b * Wn + w] != 0.f) {
                const int p = atomicAdd(&cnt, 1);
                if (p < 512) widx[b * 512 + p] = w;
            }
        }
        __syncthreads();
        if (tid == 0) wcnt[b] = cnt < 512 ? cnt : 512;
    } else if (bid == 272) {  // ---- zero gwacc ----
        for (int idx = tid; idx < 1024; idx += 256) gwacc[idx] = 0.f;
    } else {  // ---- upW -> bf16 (2 blocks, 24576 elems each) ----
        const int base = (bid - 273) * 24576;
        for (int e = base + tid * 4; e < base + 24576; e += 1024) {
            float4 v = *reinterpret_cast<const float4*>(upW + e);
            alignas(8) unsigned short u[4] = {f2bf(v.x), f2bf(v.y), f2bf(v.z), f2bf(v.w)};
            *reinterpret_cast<uint2*>(upWbf + e) = *reinterpret_cast<const uint2*>(u);
        }
    }
}

// ---------------------------------------------------------------------------
// mega_agg8: ONE WAVE = ONE SLOT, zero barriers. b = bid&7 (XCD swizzle),
// wave w of group bid>>3 handles slot i = (bid>>3)*4 + w. Wave-private LDS
// (kidx/sidx/nbL indexed [w]); within-wave DS ordering replaces barriers.
// Lane owns dims {2*lane, 2*lane+1} in gathers (no cross-lane reduce until
// the L2-norm shfl). p5: lane=(i8,j) 96 uint4 loads, shfl_xor(16/32) merge.
// ---------------------------------------------------------------------------
__global__ __launch_bounds__(256) void mega_agg8(const int* __restrict__ widx,
                                                 const int* __restrict__ wcnt,
                                                 const float* __restrict__ ww,
                                                 const float* __restrict__ wem,
                                                 const float* __restrict__ dep,
                                                 const float* __restrict__ wop,
                                                 const unsigned short* __restrict__ oph,
                                                 const unsigned short* __restrict__ wkh,
                                                 const unsigned short* __restrict__ wsh,
                                                 const unsigned short* __restrict__ upWbf,
                                                 const float* __restrict__ upb,
                                                 float* __restrict__ gwacc) {
    const int bid = blockIdx.x;
    const int b = bid & 7;                 // XCD swizzle: batch -> XCD
    const int t = threadIdx.x;
    const int lane = t & 63, w = t >> 6;
    const int i = (bid >> 3) * 4 + w;

    __shared__ int kidxL[4][512];
    __shared__ int sidxL[4][256];
    __shared__ float nbLL[4][384];
    __shared__ int knL[4], snL[4];

    if (i >= wcnt[b]) return;              // wave-uniform exit (no barriers)
    const int w_dst = widx[b * 512 + i];

    if (lane == 0) { knL[w] = 0; snL[w] = 0; }
    // same-wave DS program order makes the init visible to this wave's atomics

    // --- p1: fused ww & wem row scan (wave-coalesced) ---
    const float* wwr = ww  + ((size_t)(b * Wn + w_dst)) * Wn;
    const float* wmr = wem + ((size_t)(b * Wn + w_dst)) * Wn;
#pragma unroll
    for (int q = 0; q < 8; ++q) {
        const int e0 = q * 256 + lane * 4;
        float4 v = *reinterpret_cast<const float4*>(wwr + e0);
        float4 m = *reinterpret_cast<const float4*>(wmr + e0);
        float vv[4] = {v.x, v.y, v.z, v.w};
        float mm[4] = {m.x, m.y, m.z, m.w};
#pragma unroll
        for (int j = 0; j < 4; ++j)
            if (vv[j] != 0.f && mm[j] != 0.f) {
                const int p = atomicAdd(&knL[w], 1);
                if (p < 512) kidxL[w][p] = e0 + j;
            }
    }
    // --- dep row scan ---
    const int sD = w_dst >> 9, lD = w_dst & 511;
    const float* dr = dep + ((size_t)((sD * Bn + b) * Ln + lD)) * Ln;
#pragma unroll
    for (int q = 0; q < 2; ++q) {
        const int e0 = q * 256 + lane * 4;
        float4 v = *reinterpret_cast<const float4*>(dr + e0);
        float vv[4] = {v.x, v.y, v.z, v.w};
#pragma unroll
        for (int j = 0; j < 4; ++j)
            if (vv[j] != 0.f) {
                const int p = atomicAdd(&snL[w], 1);
                if (p < 256) sidxL[w][p] = e0 + j;
            }
    }

    // --- slot0 (operator aggregation) -> nbLL[w][0:128] ---
    {
        const float m_op = wop[((size_t)(b * Wn + w_dst)) * NOPn + lane];
        unsigned long long bal = __ballot(m_op != 0.f);
        float a0 = 0.f, a1 = 0.f;
        const unsigned short* base = oph + (size_t)b * NOPn * Hn + 2 * lane;
        while (bal) {
            const int o = __ffsll(bal) - 1;
            bal &= bal - 1;
            ushort2 v = *reinterpret_cast<const ushort2*>(base + o * Hn);
            a0 += bf2f(v.x);
            a1 += bf2f(v.y);
        }
        float ss = a0 * a0 + a1 * a1;
#pragma unroll
        for (int off = 1; off < 64; off <<= 1) ss += __shfl_xor(ss, off);
        const float sc = 1.f / (sqrtf(ss) + 1e-30f);
        nbLL[w][2 * lane]     = a0 * sc;
        nbLL[w][2 * lane + 1] = a1 * sc;
    }

    const int nk = knL[w] < 512 ? knL[w] : 512;   // after this wave's atomics
    const int ns = snL[w] < 256 ? snL[w] : 256;

    // --- slot1 (wkh gather): lane owns dims 2*lane, 2*lane+1 ---
    {
        float a0 = 0.f, a1 = 0.f;
#pragma unroll 4
        for (int p = 0; p < nk; ++p) {
            const int wd = kidxL[w][p];
            const int s = wd >> 9, l = wd & 511;
            ushort2 x = *reinterpret_cast<const ushort2*>(
                wkh + ((size_t)((s * Bn + b) * Ln + l)) * Hn + 2 * lane);
            a0 += bf2f(x.x);
            a1 += bf2f(x.y);
        }
        float ss = a0 * a0 + a1 * a1;
#pragma unroll
        for (int off = 1; off < 64; off <<= 1) ss += __shfl_xor(ss, off);
        const float sc = 1.f / (sqrtf(ss) + 1e-30f);
        nbLL[w][128 + 2 * lane]     = a0 * sc;
        nbLL[w][128 + 2 * lane + 1] = a1 * sc;
    }
    // --- slot2 (wsh gather) ---
    {
        const unsigned short* base = wsh + (size_t)((sD * Bn + b) * Ln) * Hn + 2 * lane;
        float a0 = 0.f, a1 = 0.f;
#pragma unroll 4
        for (int p = 0; p < ns; ++p) {
            ushort2 x = *reinterpret_cast<const ushort2*>(base + (size_t)sidxL[w][p] * Hn);
            a0 += bf2f(x.x);
            a1 += bf2f(x.y);
        }
        float ss = a0 * a0 + a1 * a1;
#pragma unroll
        for (int off = 1; off < 64; off <<= 1) ss += __shfl_xor(ss, off);
        const float sc = 1.f / (sqrtf(ss) + 1e-30f);
        nbLL[w][256 + 2 * lane]     = a0 * sc;
        nbLL[w][256 + 2 * lane + 1] = a1 * sc;
    }

    // --- p5: per-wave up-GEMV. lane = (i8 = (lane&15)*8, j = lane>>4);
    // k = r*4 + j over 96 rounds; uint4 = 8 bf16 per load; 8 accums;
    // j-reduction via shfl_xor(16) + shfl_xor(32); lanes 0..15 commit. ---
    {
        const int i8 = (lane & 15) * 8, j = lane >> 4;
        float a[8] = {};
#pragma unroll 8
        for (int r = 0; r < 96; ++r) {
            const int k = r * 4 + j;
            const uint4 wv4 = *reinterpret_cast<const uint4*>(upWbf + (size_t)k * 128 + i8);
            const float x = nbLL[w][k];
            a[0] = fmaf(x, bflo(wv4.x), a[0]); a[1] = fmaf(x, bfhi(wv4.x), a[1]);
            a[2] = fmaf(x, bflo(wv4.y), a[2]); a[3] = fmaf(x, bfhi(wv4.y), a[3]);
            a[4] = fmaf(x, bflo(wv4.z), a[4]); a[5] = fmaf(x, bfhi(wv4.z), a[5]);
            a[6] = fmaf(x, bflo(wv4.w), a[6]); a[7] = fmaf(x, bfhi(wv4.w), a[7]);
        }
#pragma unroll
        for (int q = 0; q < 8; ++q) {
            a[q] += __shfl_xor(a[q], 16);
            a[q] += __shfl_xor(a[q], 32);
        }
        if (lane < 16) {
#pragma unroll
            for (int q = 0; q < 8; ++q) {
                const float g = fmaxf(a[q] + upb[i8 + q], 0.f);
                atomicAdd(&gwacc[b * 128 + i8 + q], g);
            }
        }
    }
}

// ---------------------------------------------------------------------------
// final4: read pooled sums, mean, two GEMVs, gates. 8 blocks x 128 thr.
// ---------------------------------------------------------------------------
__global__ __launch_bounds__(128) void final4_k(const int* __restrict__ wcnt,
                                                const float* __restrict__ gwacc,
                                                const float* __restrict__ nh,
                                                const float* __restrict__ wgW,
                                                const float* __restrict__ wgb,
                                                const float* __restrict__ fgW,
                                                const float* __restrict__ fgb,
                                                float* __restrict__ out) {
    const int b = blockIdx.x, t = threadIdx.x;
    __shared__ float gw[Dn], nhs[Dn];
    const float inv = 1.f / ((float)wcnt[b] + 1e-30f);
    gw[t]  = gwacc[b * Dn + t] * inv;
    nhs[t] = nh[b * Dn + t];
    __syncthreads();
    float gu = wgb[t];
    for (int d = 0; d < Dn; ++d) gu = fmaf(gw[d], wgW[d * Dn + t], gu);
    gu = fmaxf(gu, 0.f);
    float fg = fgb[t];
    for (int d = 0; d < Dn; ++d) fg = fmaf(gw[d], fgW[d * Dn + t], fg);
    for (int d = 0; d < Dn; ++d) fg = fmaf(nhs[d], fgW[(Dn + d) * Dn + t], fg);
    const float forget = 1.f / (1.f + expf(-fg));
    out[b * Dn + t] = fmaxf(forget, 0.1f) * nhs[t] + (1.f - forget) * gu;
}

// ---------------------------------------------------------------------------
extern "C" void kernel_launch(void* const* d_in, const int* in_sizes, int n_in,
                              void* d_out, int out_size, void* d_ws, size_t ws_size,
                              hipStream_t stream) {
    (void)in_sizes; (void)n_in; (void)out_size; (void)ws_size;
    const float* word_outputs        = (const float*)d_in[0];
    const float* node_hidden         = (const float*)d_in[1];
    const float* op_embedding        = (const float*)d_in[2];
    const float* word_operator       = (const float*)d_in[3];
    const float* word_word           = (const float*)d_in[4];
    const float* depend_relation     = (const float*)d_in[5];
    const float* word_exist_matrix   = (const float*)d_in[6];
    const float* word_exist_sequence = (const float*)d_in[7];
    const float* goal_word           = (const float*)d_in[8];
    const float* o_w_W = (const float*)d_in[9];
    const float* o_w_b = (const float*)d_in[10];
    const float* wk_W  = (const float*)d_in[11];
    const float* wk_b  = (const float*)d_in[12];
    const float* ws_W  = (const float*)d_in[13];
    const float* ws_b  = (const float*)d_in[14];
    const float* up_W  = (const float*)d_in[15];
    const float* up_b  = (const float*)d_in[16];
    const float* wg_W  = (const float*)d_in[17];
    const float* wg_b  = (const float*)d_in[18];
    const float* fg_W  = (const float*)d_in[19];
    const float* fg_b  = (const float*)d_in[20];
    float* out = (float*)d_out;

    char* ws = (char*)d_ws;
    unsigned short* oph   = (unsigned short*)(ws + 0);                      // 128 KB
    unsigned short* wkh   = (unsigned short*)(ws + (1u << 20));             // 4 MB
    unsigned short* wsh   = (unsigned short*)(ws + (5u << 20));             // 4 MB
    int* widx             = (int*)(ws + (9u << 20));                        // 16 KB
    int* wcnt             = (int*)(ws + (9u << 20) + 32768);                // 32 B
    float* gwacc          = (float*)(ws + (9u << 20) + 65536);              // 4 KB
    unsigned short* upWbf = (unsigned short*)(ws + (9u << 20) + 131072);    // 96 KB

    prep_k<<<275, 256, 0, stream>>>(word_outputs, wk_W, ws_W, wk_b, ws_b, wkh, wsh,
                                    op_embedding, o_w_W, o_w_b, oph,
                                    goal_word, word_exist_sequence, widx, wcnt, gwacc,
                                    up_W, upWbf);
    mega_agg8<<<1024, 256, 0, stream>>>(widx, wcnt, word_word, word_exist_matrix,
                                        depend_relation, word_operator, oph, wkh, wsh,
                                        upWbf, up_b, gwacc);
    final4_k<<<8, 128, 0, stream>>>(wcnt, gwacc, node_hidden,
                                    wg_W, wg_b, fg_W, fg_b, out);
}

// Round 11
// 346.592 us; speedup vs baseline: 1.1724x; 1.1724x over previous
//
#include <hip/hip_runtime.h>
#include <math.h>

#define Sn 4
#define Bn 8
#define Ln 512
#define Dn 128
#define Hn 128
#define NOPn 64
#define Wn 2048

// ESTABLISHED: inputs fp32 insertion order; output fp32; bf16-space compare
// (thr 3.6e-2); ws = 512MB; harness tax ~220-260us/iter; poison fill 78us.
// R21 354. R22-R26: in-kernel completion schemes all lose to the kernel
// boundary. R27 350.6: bf16 upWbf + fused ww&wem + k-split. R28 345.0: wide
// loads. R29 FAIL 361.7 (2 slots/block: lost TLP). R30 339.2 (best): XCD
// swizzle b=bid&7. R31 FAIL 406 (1 wave/slot: 4x serial work, occupancy
// fell) => 4 waves/slot is the right worker shape.
// R32 (this = R30 + ballot-fused scan+gather): kill the LDS index-list
// detour. Each wave scans its quarter of ww&wem with float4, ballots hits,
// and immediately walks the mask with __ffsll, loading wkh rows (64 lanes x
// ushort2, coalesced 256B) as bits are consumed; same for dep->wsh. Removes
// kidx/sidx arrays, ~80 serialized same-address LDS atomics, the init sync,
// one barrier, and the per-row LDS readback from every block's critical path.

__device__ __forceinline__ float bf2f(unsigned short u) {
    return __uint_as_float(((unsigned int)u) << 16);
}
__device__ __forceinline__ float bflo(unsigned int u) {
    return __uint_as_float(u << 16);
}
__device__ __forceinline__ float bfhi(unsigned int u) {
    return __uint_as_float(u & 0xFFFF0000u);
}
__device__ __forceinline__ unsigned short f2bf(float f) {
    unsigned int u = __float_as_uint(f);
    return (unsigned short)((u + 0x7FFFu + ((u >> 16) & 1u)) >> 16);  // RNE
}

// ---------------------------------------------------------------------------
// prep_k: blockIdx branches.
//   0..255   : dual GEMM tile (wkh/wsh from word_outputs)
//   256..263 : op-embedding GEMM tile (oph)
//   264..271 : compact pooled indices for b = bid-264 (cap 512)
//   272      : zero gwacc
//   273..274 : convert upW (384x128 fp32) -> upWbf (bf16)
// ---------------------------------------------------------------------------
__global__ __launch_bounds__(256) void prep_k(const float* __restrict__ A,
                                              const float* __restrict__ W1,
                                              const float* __restrict__ W2,
                                              const float* __restrict__ b1,
                                              const float* __restrict__ b2,
                                              unsigned short* __restrict__ C1,
                                              unsigned short* __restrict__ C2,
                                              const float* __restrict__ ope,
                                              const float* __restrict__ owW,
                                              const float* __restrict__ owb,
                                              unsigned short* __restrict__ oph,
                                              const float* __restrict__ goal,
                                              const float* __restrict__ wes,
                                              int* __restrict__ widx,
                                              int* __restrict__ wcnt,
                                              float* __restrict__ gwacc,
                                              const float* __restrict__ upW,
                                              unsigned short* __restrict__ upWbf) {
    __shared__ __align__(16) float lA[32][68];
    __shared__ __align__(16) float lW1[32][132];
    __shared__ __align__(16) float lW2[32][132];
    __shared__ int cnt;
    const int bid = blockIdx.x, tid = threadIdx.x;

    if (bid < 256) {  // ---- dual GEMM ----
        const int m0 = bid * 64;
        float acc1[4][8] = {}, acc2[4][8] = {};
        const int r0 = (tid & 15) * 4;
        const int h0 = (tid >> 4) * 8;
        for (int k0 = 0; k0 < 128; k0 += 32) {
            __syncthreads();
            {
                const int r = tid >> 2, kk = (tid & 3) * 8;
                const float* src = A + (size_t)(m0 + r) * 128 + (k0 + kk);
                float4 v0 = reinterpret_cast<const float4*>(src)[0];
                float4 v1 = reinterpret_cast<const float4*>(src)[1];
                lA[kk + 0][r] = v0.x; lA[kk + 1][r] = v0.y;
                lA[kk + 2][r] = v0.z; lA[kk + 3][r] = v0.w;
                lA[kk + 4][r] = v1.x; lA[kk + 5][r] = v1.y;
                lA[kk + 6][r] = v1.z; lA[kk + 7][r] = v1.w;
            }
            {
                const int kk = tid >> 3, hh = (tid & 7) * 16;
                const float* s1 = W1 + (size_t)(k0 + kk) * 128 + hh;
                const float* s2 = W2 + (size_t)(k0 + kk) * 128 + hh;
#pragma unroll
                for (int q = 0; q < 4; ++q) {
                    float4 v1 = reinterpret_cast<const float4*>(s1)[q];
                    float4 v2 = reinterpret_cast<const float4*>(s2)[q];
                    lW1[kk][hh + 4 * q + 0] = v1.x; lW1[kk][hh + 4 * q + 1] = v1.y;
                    lW1[kk][hh + 4 * q + 2] = v1.z; lW1[kk][hh + 4 * q + 3] = v1.w;
                    lW2[kk][hh + 4 * q + 0] = v2.x; lW2[kk][hh + 4 * q + 1] = v2.y;
                    lW2[kk][hh + 4 * q + 2] = v2.z; lW2[kk][hh + 4 * q + 3] = v2.w;
                }
            }
            __syncthreads();
#pragma unroll
            for (int k = 0; k < 32; ++k) {
                float4 a   = *reinterpret_cast<const float4*>(&lA[k][r0]);
                float4 w10 = *reinterpret_cast<const float4*>(&lW1[k][h0]);
                float4 w11 = *reinterpret_cast<const float4*>(&lW1[k][h0 + 4]);
                float4 w20 = *reinterpret_cast<const float4*>(&lW2[k][h0]);
                float4 w21 = *reinterpret_cast<const float4*>(&lW2[k][h0 + 4]);
                float av[4] = {a.x, a.y, a.z, a.w};
                float wv1[8] = {w10.x, w10.y, w10.z, w10.w, w11.x, w11.y, w11.z, w11.w};
                float wv2[8] = {w20.x, w20.y, w20.z, w20.w, w21.x, w21.y, w21.z, w21.w};
#pragma unroll
                for (int i = 0; i < 4; ++i)
#pragma unroll
                    for (int j = 0; j < 8; ++j) {
                        acc1[i][j] = fmaf(av[i], wv1[j], acc1[i][j]);
                        acc2[i][j] = fmaf(av[i], wv2[j], acc2[i][j]);
                    }
            }
        }
#pragma unroll
        for (int i = 0; i < 4; ++i) {
            alignas(16) unsigned short u1[8], u2[8];
#pragma unroll
            for (int j = 0; j < 8; ++j) {
                u1[j] = f2bf(acc1[i][j] + b1[h0 + j]);
                u2[j] = f2bf(acc2[i][j] + b2[h0 + j]);
            }
            const size_t off = (size_t)(m0 + r0 + i) * 128 + h0;
            *reinterpret_cast<uint4*>(C1 + off) = *reinterpret_cast<const uint4*>(u1);
            *reinterpret_cast<uint4*>(C2 + off) = *reinterpret_cast<const uint4*>(u2);
        }
    } else if (bid < 264) {  // ---- oph GEMM ----
        const int m0 = (bid - 256) * 64;
        float acc[4][8] = {};
        const int r0 = (tid & 15) * 4;
        const int h0 = (tid >> 4) * 8;
        for (int k0 = 0; k0 < 128; k0 += 32) {
            __syncthreads();
            {
                const int r = tid >> 2, kk = (tid & 3) * 8;
                const float* src = ope + (size_t)(m0 + r) * 128 + (k0 + kk);
                float4 v0 = reinterpret_cast<const float4*>(src)[0];
                float4 v1 = reinterpret_cast<const float4*>(src)[1];
                lA[kk + 0][r] = v0.x; lA[kk + 1][r] = v0.y;
                lA[kk + 2][r] = v0.z; lA[kk + 3][r] = v0.w;
                lA[kk + 4][r] = v1.x; lA[kk + 5][r] = v1.y;
                lA[kk + 6][r] = v1.z; lA[kk + 7][r] = v1.w;
            }
            {
                const int kk = tid >> 3, hh = (tid & 7) * 16;
                const float* src = owW + (size_t)(k0 + kk) * 128 + hh;
#pragma unroll
                for (int q = 0; q < 4; ++q) {
                    float4 v = reinterpret_cast<const float4*>(src)[q];
                    lW1[kk][hh + 4 * q + 0] = v.x; lW1[kk][hh + 4 * q + 1] = v.y;
                    lW1[kk][hh + 4 * q + 2] = v.z; lW1[kk][hh + 4 * q + 3] = v.w;
                }
            }
            __syncthreads();
#pragma unroll
            for (int k = 0; k < 32; ++k) {
                float4 a  = *reinterpret_cast<const float4*>(&lA[k][r0]);
                float4 w0 = *reinterpret_cast<const float4*>(&lW1[k][h0]);
                float4 w1 = *reinterpret_cast<const float4*>(&lW1[k][h0 + 4]);
                float av[4] = {a.x, a.y, a.z, a.w};
                float wv[8] = {w0.x, w0.y, w0.z, w0.w, w1.x, w1.y, w1.z, w1.w};
#pragma unroll
                for (int i = 0; i < 4; ++i)
#pragma unroll
                    for (int j = 0; j < 8; ++j) acc[i][j] = fmaf(av[i], wv[j], acc[i][j]);
            }
        }
#pragma unroll
        for (int i = 0; i < 4; ++i) {
            alignas(16) unsigned short us[8];
#pragma unroll
            for (int j = 0; j < 8; ++j) us[j] = f2bf(acc[i][j] + owb[h0 + j]);
            *reinterpret_cast<uint4*>(oph + (size_t)(m0 + r0 + i) * 128 + h0) =
                *reinterpret_cast<const uint4*>(us);
        }
    } else if (bid < 272) {  // ---- compact (cap 512) ----
        const int b = bid - 264;
        if (tid == 0) cnt = 0;
        __syncthreads();
#pragma unroll
        for (int j = 0; j < 8; ++j) {
            const int w = tid * 8 + j;
            if (goal[b * Wn + w] != 0.f && wes[b * Wn + w] != 0.f) {
                const int p = atomicAdd(&cnt, 1);
                if (p < 512) widx[b * 512 + p] = w;
            }
        }
        __syncthreads();
        if (tid == 0) wcnt[b] = cnt < 512 ? cnt : 512;
    } else if (bid == 272) {  // ---- zero gwacc ----
        for (int idx = tid; idx < 1024; idx += 256) gwacc[idx] = 0.f;
    } else {  // ---- upW -> bf16 (2 blocks, 24576 elems each) ----
        const int base = (bid - 273) * 24576;
        for (int e = base + tid * 4; e < base + 24576; e += 1024) {
            float4 v = *reinterpret_cast<const float4*>(upW + e);
            alignas(8) unsigned short u[4] = {f2bf(v.x), f2bf(v.y), f2bf(v.z), f2bf(v.w)};
            *reinterpret_cast<uint2*>(upWbf + e) = *reinterpret_cast<const uint2*>(u);
        }
    }
}

// ---------------------------------------------------------------------------
// mega_agg9: one block per pooled slot (XCD swizzle b=bid&7), 4 waves/slot,
// ballot-fused scan+gather: wave wv scans ww&wem words [wv*512, wv*512+512)
// with float4, ballots each j-position, and walks the 64-bit mask with
// __ffsll loading wkh rows (64 lanes x ushort2) immediately. Same for
// dep words [wv*128, +128) -> wsh rows. No index lists, no LDS atomics,
// 3 barriers total. p4/p5 unchanged from R30.
// ---------------------------------------------------------------------------
__global__ __launch_bounds__(256) void mega_agg9(const int* __restrict__ widx,
                                                 const int* __restrict__ wcnt,
                                                 const float* __restrict__ ww,
                                                 const float* __restrict__ wem,
                                                 const float* __restrict__ dep,
                                                 const float* __restrict__ wop,
                                                 const unsigned short* __restrict__ oph,
                                                 const unsigned short* __restrict__ wkh,
                                                 const unsigned short* __restrict__ wsh,
                                                 const unsigned short* __restrict__ upWbf,
                                                 const float* __restrict__ upb,
                                                 float* __restrict__ gwacc) {
    const int bid = blockIdx.x;
    const int b = bid & 7, i = bid >> 3;   // XCD swizzle: batch -> XCD
    if (i >= wcnt[b]) return;              // uniform exit
    const int w_dst = widx[b * 512 + i];
    const int t = threadIdx.x;
    const int lane = t & 63, wv = t >> 6;

    __shared__ float part1[4][128];
    __shared__ float part2[4][128];
    __shared__ float nbL[384];
    __shared__ float gp16[16][128];

    const int sD = w_dst >> 9, lD = w_dst & 511;

    // --- slot1: ballot-fused scan(ww&wem) + gather(wkh) ---
    {
        const float* wwr = ww  + ((size_t)(b * Wn + w_dst)) * Wn;
        const float* wmr = wem + ((size_t)(b * Wn + w_dst)) * Wn;
        float a0 = 0.f, a1 = 0.f;
#pragma unroll
        for (int r = 0; r < 2; ++r) {
            const int e0 = wv * 512 + r * 256 + lane * 4;
            float4 v = *reinterpret_cast<const float4*>(wwr + e0);
            float4 m = *reinterpret_cast<const float4*>(wmr + e0);
            float vv[4] = {v.x, v.y, v.z, v.w};
            float mm[4] = {m.x, m.y, m.z, m.w};
#pragma unroll
            for (int j = 0; j < 4; ++j) {
                unsigned long long bal = __ballot(vv[j] != 0.f && mm[j] != 0.f);
                const int base = wv * 512 + r * 256 + j;
                while (bal) {
                    const int o = __ffsll(bal) - 1;
                    bal &= bal - 1;
                    const int w = base + 4 * o;
                    const int s = w >> 9, l = w & 511;
                    ushort2 x = *reinterpret_cast<const ushort2*>(
                        wkh + ((size_t)((s * Bn + b) * Ln + l)) * Hn + 2 * lane);
                    a0 += bf2f(x.x);
                    a1 += bf2f(x.y);
                }
            }
        }
        part1[wv][2 * lane]     = a0;
        part1[wv][2 * lane + 1] = a1;
    }

    // --- slot2: ballot-fused scan(dep) + gather(wsh) ---
    {
        const float* dr = dep + ((size_t)((sD * Bn + b) * Ln + lD)) * Ln;
        const unsigned short* base = wsh + (size_t)((sD * Bn + b) * Ln) * Hn + 2 * lane;
        float a0 = 0.f, a1 = 0.f;
        const int e0 = wv * 128 + lane * 2;
        float2 v = *reinterpret_cast<const float2*>(dr + e0);
        float vv[2] = {v.x, v.y};
#pragma unroll
        for (int j = 0; j < 2; ++j) {
            unsigned long long bal = __ballot(vv[j] != 0.f);
            const int lbase = wv * 128 + j;
            while (bal) {
                const int o = __ffsll(bal) - 1;
                bal &= bal - 1;
                const int l = lbase + 2 * o;
                ushort2 x = *reinterpret_cast<const ushort2*>(base + (size_t)l * Hn);
                a0 += bf2f(x.x);
                a1 += bf2f(x.y);
            }
        }
        part2[wv][2 * lane]     = a0;
        part2[wv][2 * lane + 1] = a1;
    }

    // --- slot0 (wave 3): operator aggregation -> nbL[0:128] ---
    if (wv == 3) {
        const float m_op = wop[((size_t)(b * Wn + w_dst)) * NOPn + lane];
        unsigned long long bal = __ballot(m_op != 0.f);
        float a0 = 0.f, a1 = 0.f;
        const unsigned short* base = oph + (size_t)b * NOPn * Hn + 2 * lane;
        while (bal) {
            const int o = __ffsll(bal) - 1;
            bal &= bal - 1;
            ushort2 v = *reinterpret_cast<const ushort2*>(base + o * Hn);
            a0 += bf2f(v.x);
            a1 += bf2f(v.y);
        }
        float ss = a0 * a0 + a1 * a1;
#pragma unroll
        for (int off = 1; off < 64; off <<= 1) ss += __shfl_xor(ss, off);
        const float sc = 1.f / (sqrtf(ss) + 1e-30f);
        nbL[2 * lane]     = a0 * sc;
        nbL[2 * lane + 1] = a1 * sc;
    }
    __syncthreads();

    // --- p4: reduce+normalize slot1 (wave0) and slot2 (wave1) ---
    if (wv == 0) {
        float s0 = 0.f, s1 = 0.f;
#pragma unroll
        for (int q = 0; q < 4; ++q) {
            s0 += part1[q][2 * lane];
            s1 += part1[q][2 * lane + 1];
        }
        float ss = s0 * s0 + s1 * s1;
#pragma unroll
        for (int off = 1; off < 64; off <<= 1) ss += __shfl_xor(ss, off);
        const float sc = 1.f / (sqrtf(ss) + 1e-30f);
        nbL[128 + 2 * lane]     = s0 * sc;
        nbL[128 + 2 * lane + 1] = s1 * sc;
    } else if (wv == 1) {
        float s0 = 0.f, s1 = 0.f;
#pragma unroll
        for (int q = 0; q < 4; ++q) {
            s0 += part2[q][2 * lane];
            s1 += part2[q][2 * lane + 1];
        }
        float ss = s0 * s0 + s1 * s1;
#pragma unroll
        for (int off = 1; off < 64; off <<= 1) ss += __shfl_xor(ss, off);
        const float sc = 1.f / (sqrtf(ss) + 1e-30f);
        nbL[256 + 2 * lane]     = s0 * sc;
        nbL[256 + 2 * lane + 1] = s1 * sc;
    }
    __syncthreads();

    // --- p5: wide-load up-GEMV. thread (i=t&15, j=t>>4): 8 dims i*8..i*8+7,
    // k = r*16 + j over 24 rounds; uint4 load = 8 bf16 per round. ---
    {
        const int i8 = (t & 15) * 8, j = t >> 4;
        float a[8] = {};
#pragma unroll
        for (int r = 0; r < 24; ++r) {
            const int k = r * 16 + j;
            const uint4 w = *reinterpret_cast<const uint4*>(upWbf + (size_t)k * 128 + i8);
            const float x = nbL[k];
            a[0] = fmaf(x, bflo(w.x), a[0]); a[1] = fmaf(x, bfhi(w.x), a[1]);
            a[2] = fmaf(x, bflo(w.y), a[2]); a[3] = fmaf(x, bfhi(w.y), a[3]);
            a[4] = fmaf(x, bflo(w.z), a[4]); a[5] = fmaf(x, bfhi(w.z), a[5]);
            a[6] = fmaf(x, bflo(w.w), a[6]); a[7] = fmaf(x, bfhi(w.w), a[7]);
        }
#pragma unroll
        for (int q = 0; q < 8; ++q) gp16[j][i8 + q] = a[q];
    }
    __syncthreads();
    if (t < 128) {
        float g = upb[t];
#pragma unroll
        for (int j = 0; j < 16; ++j) g += gp16[j][t];
        g = fmaxf(g, 0.f);
        atomicAdd(&gwacc[b * 128 + t], g);
    }
}

// ---------------------------------------------------------------------------
// final4: read pooled sums, mean, two GEMVs, gates. 8 blocks x 128 thr.
// ---------------------------------------------------------------------------
__global__ __launch_bounds__(128) void final4_k(const int* __restrict__ wcnt,
                                                const float* __restrict__ gwacc,
                                                const float* __restrict__ nh,
                                                const float* __restrict__ wgW,
                                                const float* __restrict__ wgb,
                                                const float* __restrict__ fgW,
                                                const float* __restrict__ fgb,
                                                float* __restrict__ out) {
    const int b = blockIdx.x, t = threadIdx.x;
    __shared__ float gw[Dn], nhs[Dn];
    const float inv = 1.f / ((float)wcnt[b] + 1e-30f);
    gw[t]  = gwacc[b * Dn + t] * inv;
    nhs[t] = nh[b * Dn + t];
    __syncthreads();
    float gu = wgb[t];
    for (int d = 0; d < Dn; ++d) gu = fmaf(gw[d], wgW[d * Dn + t], gu);
    gu = fmaxf(gu, 0.f);
    float fg = fgb[t];
    for (int d = 0; d < Dn; ++d) fg = fmaf(gw[d], fgW[d * Dn + t], fg);
    for (int d = 0; d < Dn; ++d) fg = fmaf(nhs[d], fgW[(Dn + d) * Dn + t], fg);
    const float forget = 1.f / (1.f + expf(-fg));
    out[b * Dn + t] = fmaxf(forget, 0.1f) * nhs[t] + (1.f - forget) * gu;
}

// ---------------------------------------------------------------------------
extern "C" void kernel_launch(void* const* d_in, const int* in_sizes, int n_in,
                              void* d_out, int out_size, void* d_ws, size_t ws_size,
                              hipStream_t stream) {
    (void)in_sizes; (void)n_in; (void)out_size; (void)ws_size;
    const float* word_outputs        = (const float*)d_in[0];
    const float* node_hidden         = (const float*)d_in[1];
    const float* op_embedding        = (const float*)d_in[2];
    const float* word_operator       = (const float*)d_in[3];
    const float* word_word           = (const float*)d_in[4];
    const float* depend_relation     = (const float*)d_in[5];
    const float* word_exist_matrix   = (const float*)d_in[6];
    const float* word_exist_sequence = (const float*)d_in[7];
    const float* goal_word           = (const float*)d_in[8];
    const float* o_w_W = (const float*)d_in[9];
    const float* o_w_b = (const float*)d_in[10];
    const float* wk_W  = (const float*)d_in[11];
    const float* wk_b  = (const float*)d_in[12];
    const float* ws_W  = (const float*)d_in[13];
    const float* ws_b  = (const float*)d_in[14];
    const float* up_W  = (const float*)d_in[15];
    const float* up_b  = (const float*)d_in[16];
    const float* wg_W  = (const float*)d_in[17];
    const float* wg_b  = (const float*)d_in[18];
    const float* fg_W  = (const float*)d_in[19];
    const float* fg_b  = (const float*)d_in[20];
    float* out = (float*)d_out;

    char* ws = (char*)d_ws;
    unsigned short* oph   = (unsigned short*)(ws + 0);                      // 128 KB
    unsigned short* wkh   = (unsigned short*)(ws + (1u << 20));             // 4 MB
    unsigned short* wsh   = (unsigned short*)(ws + (5u << 20));             // 4 MB
    int* widx             = (int*)(ws + (9u << 20));                        // 16 KB
    int* wcnt             = (int*)(ws + (9u << 20) + 32768);                // 32 B
    float* gwacc          = (float*)(ws + (9u << 20) + 65536);              // 4 KB
    unsigned short* upWbf = (unsigned short*)(ws + (9u << 20) + 131072);    // 96 KB

    prep_k<<<275, 256, 0, stream>>>(word_outputs, wk_W, ws_W, wk_b, ws_b, wkh, wsh,
                                    op_embedding, o_w_W, o_w_b, oph,
                                    goal_word, word_exist_sequence, widx, wcnt, gwacc,
                                    up_W, upWbf);
    mega_agg9<<<4096, 256, 0, stream>>>(widx, wcnt, word_word, word_exist_matrix,
                                        depend_relation, word_operator, oph, wkh, wsh,
                                        upWbf, up_b, gwacc);
    final4_k<<<8, 128, 0, stream>>>(wcnt, gwacc, node_hidden,
                                    wg_W, wg_b, fg_W, fg_b, out);
}

// Round 12
// 334.909 us; speedup vs baseline: 1.2133x; 1.0349x over previous
//
#include <hip/hip_runtime.h>
#include <math.h>

#define Sn 4
#define Bn 8
#define Ln 512
#define Dn 128
#define Hn 128
#define NOPn 64
#define Wn 2048

// ESTABLISHED: inputs fp32 insertion order; output fp32; bf16-space compare
// (thr 3.6e-2); ws = 512MB; harness tax ~220-260us/iter; poison fill 78us.
// R21 354. R22-R26: in-kernel completion schemes all lose. R27 350.6: bf16
// upWbf + fused ww&wem + k-split. R28 345.0: wide loads. R29 FAIL 361.7
// (2 slots/block). R30 339.2 (BEST): XCD swizzle b=bid&7. R31 FAIL 406
// (1 wave/slot). R32 FAIL 346.6 (ballot-fused gathers narrower than R30's
// ushort4 pattern) => mega locked at R30 shape.
// R33 (this): attack prep's dual GEMM (~2.1 GFLOP on fp32 VALU ~ 20-30us,
// masked by the 78us fills). Convert to bf16 MFMA (16x16x32): W staged
// transposed bf16 in LDS (WT[col][k], +4 pad), A frags direct from global,
// fragment k-layout = two 16-k halves (j<4: k=(l>>4)*4+j; j>=4: +16),
// C/D = verified col=lane&15,row=(l>>4)*4+reg. oph GEMM stays fp32.
// DECLARED RISK: A/B half-interleave layout; refcheck catches if wrong.

__device__ __forceinline__ float bf2f(unsigned short u) {
    return __uint_as_float(((unsigned int)u) << 16);
}
__device__ __forceinline__ float bflo(unsigned int u) {
    return __uint_as_float(u << 16);
}
__device__ __forceinline__ float bfhi(unsigned int u) {
    return __uint_as_float(u & 0xFFFF0000u);
}
__device__ __forceinline__ unsigned short f2bf(float f) {
    unsigned int u = __float_as_uint(f);
    return (unsigned short)((u + 0x7FFFu + ((u >> 16) & 1u)) >> 16);  // RNE
}

typedef __attribute__((ext_vector_type(8))) short bf16x8;
typedef __attribute__((ext_vector_type(4))) float f32x4;

// ---------------------------------------------------------------------------
// prep_k: blockIdx branches.
//   0..255   : dual GEMM tile via bf16 MFMA (wkh/wsh from word_outputs)
//   256..263 : op-embedding GEMM tile (oph, fp32 path)
//   264..271 : compact pooled indices for b = bid-264 (cap 512)
//   272      : zero gwacc
//   273..274 : convert upW (384x128 fp32) -> upWbf (bf16)
// ---------------------------------------------------------------------------
__global__ __launch_bounds__(256) void prep_k(const float* __restrict__ A,
                                              const float* __restrict__ W1,
                                              const float* __restrict__ W2,
                                              const float* __restrict__ b1,
                                              const float* __restrict__ b2,
                                              unsigned short* __restrict__ C1,
                                              unsigned short* __restrict__ C2,
                                              const float* __restrict__ ope,
                                              const float* __restrict__ owW,
                                              const float* __restrict__ owb,
                                              unsigned short* __restrict__ oph,
                                              const float* __restrict__ goal,
                                              const float* __restrict__ wes,
                                              int* __restrict__ widx,
                                              int* __restrict__ wcnt,
                                              float* __restrict__ gwacc,
                                              const float* __restrict__ upW,
                                              unsigned short* __restrict__ upWbf) {
    __shared__ __align__(16) unsigned char smem[33792];
    const int bid = blockIdx.x, tid = threadIdx.x;

    if (bid < 256) {  // ---- dual GEMM via MFMA ----
        unsigned short (*WT)[132] = reinterpret_cast<unsigned short(*)[132]>(smem);
        const int m0 = bid * 64;
        const int lane = tid & 63, wr = tid >> 6;
        const int rloc = lane & 15, bsel = lane >> 4;

        // hoist A fragments (row m0+wr*16+rloc), two-half k-layout per ks
        bf16x8 af[4];
        const float* Arow = A + (size_t)(m0 + wr * 16 + rloc) * 128;
#pragma unroll
        for (int ks = 0; ks < 4; ++ks) {
            float4 a0 = *reinterpret_cast<const float4*>(Arow + ks * 32 + 4 * bsel);
            float4 a1 = *reinterpret_cast<const float4*>(Arow + ks * 32 + 16 + 4 * bsel);
            af[ks][0] = (short)f2bf(a0.x); af[ks][1] = (short)f2bf(a0.y);
            af[ks][2] = (short)f2bf(a0.z); af[ks][3] = (short)f2bf(a0.w);
            af[ks][4] = (short)f2bf(a1.x); af[ks][5] = (short)f2bf(a1.y);
            af[ks][6] = (short)f2bf(a1.z); af[ks][7] = (short)f2bf(a1.w);
        }

#pragma unroll
        for (int mat = 0; mat < 2; ++mat) {
            const float* Wsrc = mat ? W2 : W1;
            const float* bias = mat ? b2 : b1;
            unsigned short* Cdst = mat ? C2 : C1;
            __syncthreads();  // protect WT before restage
            for (int idx = tid; idx < 128 * 128; idx += 256) {
                const int k = idx >> 7, c = idx & 127;
                WT[c][k] = f2bf(Wsrc[k * 128 + c]);
            }
            __syncthreads();

            f32x4 acc[8];
#pragma unroll
            for (int tl = 0; tl < 8; ++tl) acc[tl] = (f32x4){0.f, 0.f, 0.f, 0.f};
#pragma unroll
            for (int ks = 0; ks < 4; ++ks) {
#pragma unroll
                for (int tl = 0; tl < 8; ++tl) {
                    const unsigned short* p = &WT[tl * 16 + rloc][ks * 32 + 4 * bsel];
                    bf16x8 bfv;
#pragma unroll
                    for (int j = 0; j < 4; ++j) {
                        bfv[j]     = (short)p[j];
                        bfv[4 + j] = (short)p[16 + j];
                    }
                    acc[tl] = __builtin_amdgcn_mfma_f32_16x16x32_bf16(
                        af[ks], bfv, acc[tl], 0, 0, 0);
                }
            }
            // C/D: col = lane&15, row = (lane>>4)*4 + q  [verified m89/m91]
#pragma unroll
            for (int tl = 0; tl < 8; ++tl) {
                const int col = tl * 16 + rloc;
                const float bv = bias[col];
#pragma unroll
                for (int q = 0; q < 4; ++q) {
                    const int row = m0 + wr * 16 + bsel * 4 + q;
                    Cdst[(size_t)row * 128 + col] = f2bf(acc[tl][q] + bv);
                }
            }
        }
    } else if (bid < 264) {  // ---- oph GEMM (fp32 path) ----
        float (*lA)[68]   = reinterpret_cast<float(*)[68]>(smem);
        float (*lW1)[132] = reinterpret_cast<float(*)[132]>(smem + 8704);
        const int m0 = (bid - 256) * 64;
        float acc[4][8] = {};
        const int r0 = (tid & 15) * 4;
        const int h0 = (tid >> 4) * 8;
        for (int k0 = 0; k0 < 128; k0 += 32) {
            __syncthreads();
            {
                const int r = tid >> 2, kk = (tid & 3) * 8;
                const float* src = ope + (size_t)(m0 + r) * 128 + (k0 + kk);
                float4 v0 = reinterpret_cast<const float4*>(src)[0];
                float4 v1 = reinterpret_cast<const float4*>(src)[1];
                lA[kk + 0][r] = v0.x; lA[kk + 1][r] = v0.y;
                lA[kk + 2][r] = v0.z; lA[kk + 3][r] = v0.w;
                lA[kk + 4][r] = v1.x; lA[kk + 5][r] = v1.y;
                lA[kk + 6][r] = v1.z; lA[kk + 7][r] = v1.w;
            }
            {
                const int kk = tid >> 3, hh = (tid & 7) * 16;
                const float* src = owW + (size_t)(k0 + kk) * 128 + hh;
#pragma unroll
                for (int q = 0; q < 4; ++q) {
                    float4 v = reinterpret_cast<const float4*>(src)[q];
                    lW1[kk][hh + 4 * q + 0] = v.x; lW1[kk][hh + 4 * q + 1] = v.y;
                    lW1[kk][hh + 4 * q + 2] = v.z; lW1[kk][hh + 4 * q + 3] = v.w;
                }
            }
            __syncthreads();
#pragma unroll
            for (int k = 0; k < 32; ++k) {
                float4 a  = *reinterpret_cast<const float4*>(&lA[k][r0]);
                float4 w0 = *reinterpret_cast<const float4*>(&lW1[k][h0]);
                float4 w1 = *reinterpret_cast<const float4*>(&lW1[k][h0 + 4]);
                float av[4] = {a.x, a.y, a.z, a.w};
                float wv[8] = {w0.x, w0.y, w0.z, w0.w, w1.x, w1.y, w1.z, w1.w};
#pragma unroll
                for (int i = 0; i < 4; ++i)
#pragma unroll
                    for (int j = 0; j < 8; ++j) acc[i][j] = fmaf(av[i], wv[j], acc[i][j]);
            }
        }
#pragma unroll
        for (int i = 0; i < 4; ++i) {
            alignas(16) unsigned short us[8];
#pragma unroll
            for (int j = 0; j < 8; ++j) us[j] = f2bf(acc[i][j] + owb[h0 + j]);
            *reinterpret_cast<uint4*>(oph + (size_t)(m0 + r0 + i) * 128 + h0) =
                *reinterpret_cast<const uint4*>(us);
        }
    } else if (bid < 272) {  // ---- compact (cap 512) ----
        int* cnt = reinterpret_cast<int*>(smem);
        const int b = bid - 264;
        if (tid == 0) *cnt = 0;
        __syncthreads();
#pragma unroll
        for (int j = 0; j < 8; ++j) {
            const int w = tid * 8 + j;
            if (goal[b * Wn + w] != 0.f && wes[b * Wn + w] != 0.f) {
                const int p = atomicAdd(cnt, 1);
                if (p < 512) widx[b * 512 + p] = w;
            }
        }
        __syncthreads();
        if (tid == 0) wcnt[b] = *cnt < 512 ? *cnt : 512;
    } else if (bid == 272) {  // ---- zero gwacc ----
        for (int idx = tid; idx < 1024; idx += 256) gwacc[idx] = 0.f;
    } else {  // ---- upW -> bf16 (2 blocks, 24576 elems each) ----
        const int base = (bid - 273) * 24576;
        for (int e = base + tid * 4; e < base + 24576; e += 1024) {
            float4 v = *reinterpret_cast<const float4*>(upW + e);
            alignas(8) unsigned short u[4] = {f2bf(v.x), f2bf(v.y), f2bf(v.z), f2bf(v.w)};
            *reinterpret_cast<uint2*>(upWbf + e) = *reinterpret_cast<const uint2*>(u);
        }
    }
}

// ---------------------------------------------------------------------------
// mega_agg7 (R30, best): one block per pooled slot, XCD-swizzled b=bid&7.
// Wide loads: ushort4 gathers (2 rows/wave/iter), uint4 GEMV w/ [16][128]
// LDS tile. 3 barriers. No completion machinery.
// ---------------------------------------------------------------------------
__global__ __launch_bounds__(256) void mega_agg7(const int* __restrict__ widx,
                                                 const int* __restrict__ wcnt,
                                                 const float* __restrict__ ww,
                                                 const float* __restrict__ wem,
                                                 const float* __restrict__ dep,
                                                 const float* __restrict__ wop,
                                                 const unsigned short* __restrict__ oph,
                                                 const unsigned short* __restrict__ wkh,
                                                 const unsigned short* __restrict__ wsh,
                                                 const unsigned short* __restrict__ upWbf,
                                                 const float* __restrict__ upb,
                                                 float* __restrict__ gwacc) {
    const int bid = blockIdx.x;
    const int b = bid & 7, i = bid >> 3;  // XCD swizzle: batch -> XCD
    if (i >= wcnt[b]) return;             // uniform exit
    const int w_dst = widx[b * 512 + i];
    const int t = threadIdx.x;
    const int lane = t & 63, wv = t >> 6;

    __shared__ int kidx[512];
    __shared__ int sidx[256];
    __shared__ int kn, sn;
    __shared__ float part1[4][128];
    __shared__ float part2[4][128];
    __shared__ float nbL[384];
    __shared__ float gp16[16][128];
    if (t == 0) { kn = 0; sn = 0; }
    __syncthreads();

    // --- p1: fused ww & wem row streams + dep row scan ---
    const float* wwr = ww  + ((size_t)(b * Wn + w_dst)) * Wn;
    const float* wmr = wem + ((size_t)(b * Wn + w_dst)) * Wn;
#pragma unroll
    for (int q = 0; q < 2; ++q) {
        const int e0 = q * 1024 + t * 4;
        float4 v = *reinterpret_cast<const float4*>(wwr + e0);
        float4 m = *reinterpret_cast<const float4*>(wmr + e0);
        float vv[4] = {v.x, v.y, v.z, v.w};
        float mm[4] = {m.x, m.y, m.z, m.w};
#pragma unroll
        for (int j = 0; j < 4; ++j)
            if (vv[j] != 0.f && mm[j] != 0.f) {
                int p = atomicAdd(&kn, 1);
                if (p < 512) kidx[p] = e0 + j;
            }
    }
    const int sD = w_dst >> 9, lD = w_dst & 511;
    if (t < 128) {
        const float* dr = dep + ((size_t)((sD * Bn + b) * Ln + lD)) * Ln + t * 4;
        float4 v = *reinterpret_cast<const float4*>(dr);
        float vv[4] = {v.x, v.y, v.z, v.w};
#pragma unroll
        for (int j = 0; j < 4; ++j)
            if (vv[j] != 0.f) {
                int p = atomicAdd(&sn, 1);
                if (p < 256) sidx[p] = t * 4 + j;
            }
    }
    float m_op = 0.f;
    if (wv == 3) m_op = wop[((size_t)(b * Wn + w_dst)) * NOPn + lane];
    __syncthreads();

    const int nk = kn < 512 ? kn : 512;
    const int ns = sn < 256 ? sn : 256;

    // --- p3: gathers (ushort4/lane, 2 rows per wave per iteration) ---
    {   // slot1
        const int hl = lane >> 5, c = lane & 31;
        float a0 = 0.f, a1 = 0.f, a2 = 0.f, a3 = 0.f;
        for (int p = wv * 2 + hl; p < nk; p += 8) {
            const int w = kidx[p];
            const int s = w >> 9, l = w & 511;
            ushort4 x = *reinterpret_cast<const ushort4*>(
                wkh + ((size_t)((s * Bn + b) * Ln + l)) * Hn + c * 4);
            a0 += bf2f(x.x); a1 += bf2f(x.y); a2 += bf2f(x.z); a3 += bf2f(x.w);
        }
        a0 += __shfl_xor(a0, 32); a1 += __shfl_xor(a1, 32);
        a2 += __shfl_xor(a2, 32); a3 += __shfl_xor(a3, 32);
        if (hl == 0) {
            part1[wv][c * 4 + 0] = a0; part1[wv][c * 4 + 1] = a1;
            part1[wv][c * 4 + 2] = a2; part1[wv][c * 4 + 3] = a3;
        }
    }
    {   // slot2
        const int hl = lane >> 5, c = lane & 31;
        const unsigned short* base = wsh + (size_t)((sD * Bn + b) * Ln) * Hn + c * 4;
        float a0 = 0.f, a1 = 0.f, a2 = 0.f, a3 = 0.f;
        for (int p = wv * 2 + hl; p < ns; p += 8) {
            ushort4 x = *reinterpret_cast<const ushort4*>(base + (size_t)sidx[p] * Hn);
            a0 += bf2f(x.x); a1 += bf2f(x.y); a2 += bf2f(x.z); a3 += bf2f(x.w);
        }
        a0 += __shfl_xor(a0, 32); a1 += __shfl_xor(a1, 32);
        a2 += __shfl_xor(a2, 32); a3 += __shfl_xor(a3, 32);
        if (hl == 0) {
            part2[wv][c * 4 + 0] = a0; part2[wv][c * 4 + 1] = a1;
            part2[wv][c * 4 + 2] = a2; part2[wv][c * 4 + 3] = a3;
        }
    }
    if (wv == 3) {  // slot0 -> nbL[0:128]
        unsigned long long bal = __ballot(m_op != 0.f);
        float a0 = 0.f, a1 = 0.f;
        const unsigned short* base = oph + (size_t)b * NOPn * Hn + 2 * lane;
        while (bal) {
            const int o = __ffsll(bal) - 1;
            bal &= bal - 1;
            ushort2 v = *reinterpret_cast<const ushort2*>(base + o * Hn);
            a0 += bf2f(v.x);
            a1 += bf2f(v.y);
        }
        float ss = a0 * a0 + a1 * a1;
#pragma unroll
        for (int off = 1; off < 64; off <<= 1) ss += __shfl_xor(ss, off);
        const float sc = 1.f / (sqrtf(ss) + 1e-30f);
        nbL[2 * lane]     = a0 * sc;
        nbL[2 * lane + 1] = a1 * sc;
    }
    __syncthreads();

    // --- p4: reduce+normalize slot1 (wave0) and slot2 (wave1) ---
    if (wv == 0) {
        float s0 = 0.f, s1 = 0.f;
#pragma unroll
        for (int q = 0; q < 4; ++q) {
            s0 += part1[q][2 * lane];
            s1 += part1[q][2 * lane + 1];
        }
        float ss = s0 * s0 + s1 * s1;
#pragma unroll
        for (int off = 1; off < 64; off <<= 1) ss += __shfl_xor(ss, off);
        const float sc = 1.f / (sqrtf(ss) + 1e-30f);
        nbL[128 + 2 * lane]     = s0 * sc;
        nbL[128 + 2 * lane + 1] = s1 * sc;
    } else if (wv == 1) {
        float s0 = 0.f, s1 = 0.f;
#pragma unroll
        for (int q = 0; q < 4; ++q) {
            s0 += part2[q][2 * lane];
            s1 += part2[q][2 * lane + 1];
        }
        float ss = s0 * s0 + s1 * s1;
#pragma unroll
        for (int off = 1; off < 64; off <<= 1) ss += __shfl_xor(ss, off);
        const float sc = 1.f / (sqrtf(ss) + 1e-30f);
        nbL[256 + 2 * lane]     = s0 * sc;
        nbL[256 + 2 * lane + 1] = s1 * sc;
    }
    __syncthreads();

    // --- p5: wide-load up-GEMV. thread (i=t&15, j=t>>4): 8 dims i*8..i*8+7,
    // k = r*16 + j over 24 rounds; uint4 load = 8 bf16 per round. ---
    {
        const int i8 = (t & 15) * 8, j = t >> 4;
        float a[8] = {};
#pragma unroll
        for (int r = 0; r < 24; ++r) {
            const int k = r * 16 + j;
            const uint4 w = *reinterpret_cast<const uint4*>(upWbf + (size_t)k * 128 + i8);
            const float x = nbL[k];
            a[0] = fmaf(x, bflo(w.x), a[0]); a[1] = fmaf(x, bfhi(w.x), a[1]);
            a[2] = fmaf(x, bflo(w.y), a[2]); a[3] = fmaf(x, bfhi(w.y), a[3]);
            a[4] = fmaf(x, bflo(w.z), a[4]); a[5] = fmaf(x, bfhi(w.z), a[5]);
            a[6] = fmaf(x, bflo(w.w), a[6]); a[7] = fmaf(x, bfhi(w.w), a[7]);
        }
#pragma unroll
        for (int q = 0; q < 8; ++q) gp16[j][i8 + q] = a[q];
    }
    __syncthreads();
    if (t < 128) {
        float g = upb[t];
#pragma unroll
        for (int j = 0; j < 16; ++j) g += gp16[j][t];
        g = fmaxf(g, 0.f);
        atomicAdd(&gwacc[b * 128 + t], g);
    }
}

// ---------------------------------------------------------------------------
// final4: read pooled sums, mean, two GEMVs, gates. 8 blocks x 128 thr.
// ---------------------------------------------------------------------------
__global__ __launch_bounds__(128) void final4_k(const int* __restrict__ wcnt,
                                                const float* __restrict__ gwacc,
                                                const float* __restrict__ nh,
                                                const float* __restrict__ wgW,
                                                const float* __restrict__ wgb,
                                                const float* __restrict__ fgW,
                                                const float* __restrict__ fgb,
                                                float* __restrict__ out) {
    const int b = blockIdx.x, t = threadIdx.x;
    __shared__ float gw[Dn], nhs[Dn];
    const float inv = 1.f / ((float)wcnt[b] + 1e-30f);
    gw[t]  = gwacc[b * Dn + t] * inv;
    nhs[t] = nh[b * Dn + t];
    __syncthreads();
    float gu = wgb[t];
    for (int d = 0; d < Dn; ++d) gu = fmaf(gw[d], wgW[d * Dn + t], gu);
    gu = fmaxf(gu, 0.f);
    float fg = fgb[t];
    for (int d = 0; d < Dn; ++d) fg = fmaf(gw[d], fgW[d * Dn + t], fg);
    for (int d = 0; d < Dn; ++d) fg = fmaf(nhs[d], fgW[(Dn + d) * Dn + t], fg);
    const float forget = 1.f / (1.f + expf(-fg));
    out[b * Dn + t] = fmaxf(forget, 0.1f) * nhs[t] + (1.f - forget) * gu;
}

// ---------------------------------------------------------------------------
extern "C" void kernel_launch(void* const* d_in, const int* in_sizes, int n_in,
                              void* d_out, int out_size, void* d_ws, size_t ws_size,
                              hipStream_t stream) {
    (void)in_sizes; (void)n_in; (void)out_size; (void)ws_size;
    const float* word_outputs        = (const float*)d_in[0];
    const float* node_hidden         = (const float*)d_in[1];
    const float* op_embedding        = (const float*)d_in[2];
    const float* word_operator       = (const float*)d_in[3];
    const float* word_word           = (const float*)d_in[4];
    const float* depend_relation     = (const float*)d_in[5];
    const float* word_exist_matrix   = (const float*)d_in[6];
    const float* word_exist_sequence = (const float*)d_in[7];
    const float* goal_word           = (const float*)d_in[8];
    const float* o_w_W = (const float*)d_in[9];
    const float* o_w_b = (const float*)d_in[10];
    const float* wk_W  = (const float*)d_in[11];
    const float* wk_b  = (const float*)d_in[12];
    const float* ws_W  = (const float*)d_in[13];
    const float* ws_b  = (const float*)d_in[14];
    const float* up_W  = (const float*)d_in[15];
    const float* up_b  = (const float*)d_in[16];
    const float* wg_W  = (const float*)d_in[17];
    const float* wg_b  = (const float*)d_in[18];
    const float* fg_W  = (const float*)d_in[19];
    const float* fg_b  = (const float*)d_in[20];
    float* out = (float*)d_out;

    char* ws = (char*)d_ws;
    unsigned short* oph   = (unsigned short*)(ws + 0);                      // 128 KB
    unsigned short* wkh   = (unsigned short*)(ws + (1u << 20));             // 4 MB
    unsigned short* wsh   = (unsigned short*)(ws + (5u << 20));             // 4 MB
    int* widx             = (int*)(ws + (9u << 20));                        // 16 KB
    int* wcnt             = (int*)(ws + (9u << 20) + 32768);                // 32 B
    float* gwacc          = (float*)(ws + (9u << 20) + 65536);              // 4 KB
    unsigned short* upWbf = (unsigned short*)(ws + (9u << 20) + 131072);    // 96 KB

    prep_k<<<275, 256, 0, stream>>>(word_outputs, wk_W, ws_W, wk_b, ws_b, wkh, wsh,
                                    op_embedding, o_w_W, o_w_b, oph,
                                    goal_word, word_exist_sequence, widx, wcnt, gwacc,
                                    up_W, upWbf);
    mega_agg7<<<4096, 256, 0, stream>>>(widx, wcnt, word_word, word_exist_matrix,
                                        depend_relation, word_operator, oph, wkh, wsh,
                                        upWbf, up_b, gwacc);
    final4_k<<<8, 128, 0, stream>>>(wcnt, gwacc, node_hidden,
                                    wg_W, wg_b, fg_W, fg_b, out);
}